// Round 3
// baseline (134.553 us; speedup 1.0000x reference)
//
#include <hip/hip_runtime.h>
#include <hip/hip_bf16.h>
#include <cmath>

// ---------------------------------------------------------------------------
// Noisy 8-qubit density-matrix circuit in the Pauli transfer basis.
// State: R[p0..p7], p in {I,X,Y,Z}, 4^8 = 65536 reals, fp16 in dynamic LDS.
// Qubit q <-> base-4 digit with stride 4^(7-q) (qubit 0 most significant).
// Each single-qubit (gate+noise) composite = real 4x4 along one axis.
// rzz = 4 in-plane rotations + per-qubit affine noise on both axes.
// <Z_0> = R[Z,I,...,I] = element 3*4^7.
// OUTPUT IS FLOAT32 (reference computes in f32; harness reads f32).
// ---------------------------------------------------------------------------

typedef _Float16 h8 __attribute__((ext_vector_type(8)));

static constexpr int NT = 512;
static constexpr int STATE = 65536;            // 4^8
static constexpr int SMEM_BYTES = STATE * 2;   // fp16 state = 128 KiB dynamic LDS

struct M12 { float m[12]; };  // rows X,Y,Z of a PTM (row I is always (1,0,0,0))

__device__ __forceinline__ void mul4(const float* A, const float* B, float* C) {
  #pragma unroll
  for (int i = 0; i < 4; i++) {
    #pragma unroll
    for (int j = 0; j < 4; j++) {
      float s = 0.f;
      #pragma unroll
      for (int k = 0; k < 4; k++) s += A[i*4+k] * B[k*4+j];
      C[i*4+j] = s;
    }
  }
}

// rot_block composite: rz(phi) -> rx(th) -> rz(al), each with its noise.
// ang = (theta, phi, alpha) as stored in quanum_weights.
__device__ __forceinline__ M12 rotM(const float* ang, float lam1,
                                    float k1, float g1, float h1) {
  float s1, c1, s2, c2, s3, c3;
  sincosf(ang[1], &s1, &c1);   // phi   (first rz)
  sincosf(ang[0], &s2, &c2);   // theta (rx)
  sincosf(ang[2], &s3, &c3);   // alpha (last rz)
  float Z1[16] = {1,0,0,0, 0,lam1*c1,-lam1*s1,0, 0,lam1*s1,lam1*c1,0, 0,0,0,lam1};
  float BR[16] = {1,0,0,0, 0,k1,0,0, 0,0,k1*c2,-k1*s2, g1,0,h1*s2,h1*c2};
  float Z2[16] = {1,0,0,0, 0,lam1*c3,-lam1*s3,0, 0,lam1*s3,lam1*c3,0, 0,0,0,lam1};
  float T1[16], T2[16];
  mul4(BR, Z1, T1);            // T1 = BR * Z1
  mul4(Z2, T1, T2);            // T2 = Z2 * BR * Z1  (applied right-to-left)
  M12 M;
  #pragma unroll
  for (int i = 0; i < 12; i++) M.m[i] = T2[4 + i];
  return M;
}

// Fused rzz superoperator core on a 16-vector f[a*4+b] (a = qubit q, b = q+1).
// Verified against explicit state-vector checks (|++>, theta=pi/2).
__device__ __forceinline__ void zzcore(float* f, float c2, float s2,
                                       float nn, float gg, float hh) {
  float t;
  t = c2*f[4]  - s2*f[11]; f[11] = s2*f[4]  + c2*f[11]; f[4]  = t;  // XI / YZ
  t = c2*f[7]  - s2*f[8];  f[8]  = s2*f[7]  + c2*f[8];  f[7]  = t;  // XZ / YI
  t = c2*f[1]  - s2*f[14]; f[14] = s2*f[1]  + c2*f[14]; f[1]  = t;  // IX / ZY
  t = c2*f[13] - s2*f[2];  f[2]  = s2*f[13] + c2*f[2];  f[13] = t;  // ZX / IY
  #pragma unroll
  for (int b = 0; b < 4; b++) { f[4+b] *= nn; f[8+b] *= nn; f[12+b] = gg*f[b] + hh*f[12+b]; }
  #pragma unroll
  for (int a = 0; a < 4; a++) { f[a*4+1] *= nn; f[a*4+2] *= nn; f[a*4+3] = gg*f[a*4] + hh*f[a*4+3]; }
}

// Apply a single-qubit PTM (rows X,Y,Z in M) along axis q. In-place over
// disjoint 4-element fibers at stride 4^(7-q); row I is identity => untouched.
__device__ __forceinline__ void apply1(_Float16* st, const M12 M, int q, int tid) {
  if (q <= 5) {                       // stride >= 16: vectorize 8 along inner index
    const int sh = 2*(7-q);
    const int stride = 1 << sh;
    for (int g = tid; g < 2048; g += NT) {
      const int r = g & ((stride >> 3) - 1);
      const int o = g >> (sh - 3);
      const int base = (o << (sh+2)) + (r << 3);
      h8 v0 = *(h8*)(st + base);
      h8 v1 = *(h8*)(st + base + stride);
      h8 v2 = *(h8*)(st + base + 2*stride);
      h8 v3 = *(h8*)(st + base + 3*stride);
      h8 o1, o2, o3;
      #pragma unroll
      for (int j = 0; j < 8; j++) {
        const float a=(float)v0[j], b=(float)v1[j], c=(float)v2[j], d=(float)v3[j];
        o1[j] = (_Float16)(M.m[0]*a + M.m[1]*b + M.m[2]*c  + M.m[3]*d);
        o2[j] = (_Float16)(M.m[4]*a + M.m[5]*b + M.m[6]*c  + M.m[7]*d);
        o3[j] = (_Float16)(M.m[8]*a + M.m[9]*b + M.m[10]*c + M.m[11]*d);
      }
      *(h8*)(st + base + stride)   = o1;
      *(h8*)(st + base + 2*stride) = o2;
      *(h8*)(st + base + 3*stride) = o3;
    }
  } else if (q == 6) {                // stride 4: 16-consecutive block = 4 fibers
    for (int o = tid; o < 4096; o += NT) {
      const int base = o << 4;
      h8 u0 = *(h8*)(st + base), u1 = *(h8*)(st + base + 8);
      h8 w0 = u0, w1 = u1;
      #pragma unroll
      for (int i = 0; i < 4; i++) {
        const float a=(float)u0[i], b=(float)u0[4+i], c=(float)u1[i], d=(float)u1[4+i];
        w0[4+i] = (_Float16)(M.m[0]*a + M.m[1]*b + M.m[2]*c  + M.m[3]*d);
        w1[i]   = (_Float16)(M.m[4]*a + M.m[5]*b + M.m[6]*c  + M.m[7]*d);
        w1[4+i] = (_Float16)(M.m[8]*a + M.m[9]*b + M.m[10]*c + M.m[11]*d);
      }
      *(h8*)(st + base) = w0; *(h8*)(st + base + 8) = w1;
    }
  } else {                            // q == 7, stride 1: 2 fibers per h8
    for (int t = tid; t < 8192; t += NT) {
      const int base = t << 3;
      h8 u = *(h8*)(st + base);
      h8 w = u;
      #pragma unroll
      for (int f2 = 0; f2 < 2; f2++) {
        const float a=(float)u[4*f2], b=(float)u[4*f2+1], c=(float)u[4*f2+2], d=(float)u[4*f2+3];
        w[4*f2+1] = (_Float16)(M.m[0]*a + M.m[1]*b + M.m[2]*c  + M.m[3]*d);
        w[4*f2+2] = (_Float16)(M.m[4]*a + M.m[5]*b + M.m[6]*c  + M.m[7]*d);
        w[4*f2+3] = (_Float16)(M.m[8]*a + M.m[9]*b + M.m[10]*c + M.m[11]*d);
      }
      *(h8*)(st + base) = w;
    }
  }
}

// Fused noisy_rzz on qubit pair (q, q+1). S4 = 4^(6-q) = stride of qubit q+1.
__device__ __forceinline__ void applyZZ(_Float16* st, float c2, float s2,
                                        float nn, float gg, float hh, int q, int tid) {
  if (q <= 4) {                       // S4 >= 16: vectorize 8 along inner index
    const int sh4 = 2*(6-q);
    const int S4 = 1 << sh4;
    for (int g = tid; g < 512; g += NT) {
      const int r = g & ((S4 >> 3) - 1);
      const int o = g >> (sh4 - 3);
      const int base = (o << (sh4+4)) + (r << 3);
      h8 v[16];
      #pragma unroll
      for (int a = 0; a < 4; a++)
        #pragma unroll
        for (int bq = 0; bq < 4; bq++)
          v[a*4+bq] = *(h8*)(st + base + a*(S4<<2) + bq*S4);
      #pragma unroll
      for (int j = 0; j < 8; j++) {
        float f[16];
        #pragma unroll
        for (int m = 0; m < 16; m++) f[m] = (float)v[m][j];
        zzcore(f, c2, s2, nn, gg, hh);
        #pragma unroll
        for (int m = 1; m < 16; m++) v[m][j] = (_Float16)f[m];
      }
      #pragma unroll
      for (int a = 0; a < 4; a++)
        #pragma unroll
        for (int bq = 0; bq < 4; bq++)
          if (a | bq) *(h8*)(st + base + a*(S4<<2) + bq*S4) = v[a*4+bq];
    }
  } else if (q == 5) {                // S4 = 4: 64-consecutive block per o
    for (int o = tid; o < 1024; o += NT) {
      const int base = o << 6;
      h8 u[8];
      #pragma unroll
      for (int m = 0; m < 8; m++) u[m] = *(h8*)(st + base + m*8);
      #pragma unroll
      for (int i = 0; i < 4; i++) {
        float f[16];
        #pragma unroll
        for (int a = 0; a < 4; a++)
          #pragma unroll
          for (int bq = 0; bq < 4; bq++)
            f[a*4+bq] = (float)u[a*2 + (bq>>1)][(bq&1)*4 + i];
        zzcore(f, c2, s2, nn, gg, hh);
        #pragma unroll
        for (int a = 0; a < 4; a++)
          #pragma unroll
          for (int bq = 0; bq < 4; bq++)
            u[a*2 + (bq>>1)][(bq&1)*4 + i] = (_Float16)f[a*4+bq];
      }
      #pragma unroll
      for (int m = 0; m < 8; m++) *(h8*)(st + base + m*8) = u[m];
    }
  } else {                            // q == 6: 16 consecutive = full [a][b] block
    for (int o = tid; o < 4096; o += NT) {
      const int base = o << 4;
      h8 u0 = *(h8*)(st + base), u1 = *(h8*)(st + base + 8);
      float f[16];
      #pragma unroll
      for (int m = 0; m < 8; m++) { f[m] = (float)u0[m]; f[8+m] = (float)u1[m]; }
      zzcore(f, c2, s2, nn, gg, hh);
      #pragma unroll
      for (int m = 0; m < 8; m++) { u0[m] = (_Float16)f[m]; u1[m] = (_Float16)f[8+m]; }
      *(h8*)(st + base) = u0; *(h8*)(st + base + 8) = u1;
    }
  }
}

__global__ __launch_bounds__(NT) void qnn_kernel(
    const float* __restrict__ x, const float* __restrict__ fminp,
    const float* __restrict__ qw, const float* __restrict__ dk,
    const float* __restrict__ db, float* __restrict__ out,
    float lam1, float k1f, float g1f, float h1f,
    float n2f, float g2f, float h2f) {
  extern __shared__ _Float16 st[];   // ONLY dynamic LDS

  const int tid = threadIdx.x;
  const int b = blockIdx.x;

  // ---- zero the state ----
  for (int i = tid; i < STATE/8; i += NT)
    *(uint4*)(st + i*8) = make_uint4(0u, 0u, 0u, 0u);
  __syncthreads();

  // ---- initial state |0..0><0..0|: R[p]=1 iff all digits in {I,Z} ----
  if (tid < 256) {
    int p = 0;
    #pragma unroll
    for (int k = 0; k < 8; k++) if ((tid >> k) & 1) p |= 3 << (2*k);
    st[p] = (_Float16)1.0f;
  }
  __syncthreads();

  const float fm = fminp[0];

  // ---- encoding: noisy_rx(x_q * fmin) on each qubit ----
  for (int q = 0; q < 8; q++) {
    float s, c;
    sincosf(x[b*8 + q] * fm, &s, &c);
    M12 M = {{0, k1f, 0, 0,   0, 0, k1f*c, -k1f*s,   g1f, 0, h1f*s, h1f*c}};
    apply1(st, M, q, tid);
    __syncthreads();
  }

  // ---- 2 layers: rot_blocks then rzz chain ----
  for (int l = 0; l < 2; l++) {
    for (int q = 0; q < 8; q++) {
      M12 M = rotM(qw + (l*8 + q)*3, lam1, k1f, g1f, h1f);  // w[0][l][q]
      apply1(st, M, q, tid);
      __syncthreads();
    }
    for (int q = 0; q < 7; q++) {
      float s, c;
      sincosf(qw[48 + l*7 + q], &s, &c);                    // e[0][l][q]
      applyZZ(st, c, s, n2f, g2f, h2f, q, tid);
      __syncthreads();
    }
  }

  // ---- final rot_blocks (fin[q] at qw[62 + q*3]) ----
  for (int q = 0; q < 8; q++) {
    M12 M = rotM(qw + 62 + q*3, lam1, k1f, g1f, h1f);
    apply1(st, M, q, tid);
    __syncthreads();
  }

  // ---- <Z_0> = R[Z,I,...,I]; dense layer; FLOAT32 output ----
  if (tid == 0) {
    const float z = (float)st[3 * 16384];
    out[b] = z * dk[0] + db[0];
  }
}

extern "C" void kernel_launch(void* const* d_in, const int* in_sizes, int n_in,
                              void* d_out, int out_size, void* d_ws, size_t ws_size,
                              hipStream_t stream) {
  (void)n_in; (void)d_ws; (void)ws_size; (void)out_size;
  const float* x    = (const float*)d_in[0];   // (64,8)
  const float* fmin = (const float*)d_in[1];   // (1,)
  const float* qw   = (const float*)d_in[2];   // (86,)
  const float* dk   = (const float*)d_in[3];   // (1,1)
  const float* db   = (const float*)d_in[4];   // (1,)
  float* out = (float*)d_out;                  // float32 output (B,1)

  const int B = in_sizes[0] / 8;

  // IBM Kingston noise constants (double precision on host).
  const double EPC1 = 0.0002335, EPC2 = 0.002137;
  const double T1 = 0.00022438, T2 = 0.00012053;
  const double TRX = 3.5e-8, TZZ = 2.5e-7;
  const double lam1 = 1.0 - 4.0*EPC1/3.0;          // depol1: X,Y,Z scale
  const double lam2 = 1.0 - 4.0*EPC2/3.0;          // depol2
  const double gad1 = 1.0 - exp(-TRX/T1);          // AD gamma (rx)
  const double gpd1 = 1.0 - exp(-TRX/T2);          // PD gamma (rx)
  const double gad2 = 1.0 - exp(-TZZ/T1);          // AD gamma (rzz)
  const double gpd2 = 1.0 - exp(-TZZ/T2);          // PD gamma (rzz)
  // Composite PD*AD*Depol (applied after the gate):
  //   X,Y scale k; Z row: g*I + h*Z.
  const float k1f = (float)(sqrt((1.0-gpd1)*(1.0-gad1)) * lam1);
  const float g1f = (float)gad1;
  const float h1f = (float)((1.0-gad1) * lam1);
  const float n2f = (float)(sqrt((1.0-gpd2)*(1.0-gad2)) * lam2);
  const float g2f = (float)gad2;
  const float h2f = (float)((1.0-gad2) * lam2);

  hipFuncSetAttribute(reinterpret_cast<const void*>(qnn_kernel),
                      hipFuncAttributeMaxDynamicSharedMemorySize, SMEM_BYTES);
  qnn_kernel<<<B, NT, SMEM_BYTES, stream>>>(x, fmin, qw, dk, db, out,
                                            (float)lam1, k1f, g1f, h1f,
                                            n2f, g2f, h2f);
}

// Round 4
// 12.708 us; speedup vs baseline: 10.5883x; 10.5883x over previous
//
#include <hip/hip_runtime.h>
#include <cmath>

// ---------------------------------------------------------------------------
// Light-cone-reduced noisy QNN.
//
// Only <Z_0> is measured. Backward (Heisenberg) propagation of Z_0 through
// the reverse program, skipping trace-preserving channels with disjoint
// support (their dual fixes A (x) I), gives support {q0,q1,q2}:
//   reverse order: FINrot0^T, L2zz01^T, L2rot1^T, L2rot0^T,
//                  L1zz12^T, L1zz01^T, L1rot2^T, L1rot1^T, L1rot0^T
// acting on a 64-dim real Pauli-coefficient vector w[p0*16+p1*4+p2]
// (batch-independent). The encoded state is a product state, so
//   out_b = ( sum_p w[p] * r0[p0]*r1[p1]*r2[p2] ) * dk + db,
//   r_q = (1, 0, -k1*sin(x_q*fmin), g1 + h1*cos(x_q*fmin)).
// Dual maps: transposed PTMs (rotation blocks: s -> -s; AD dual: wI += g*wZ).
// All f32, all in registers, one 64-thread block, no LDS, no barriers.
// ---------------------------------------------------------------------------

static __device__ __forceinline__ void mul4(const float* A, const float* B, float* C) {
  #pragma unroll
  for (int i = 0; i < 4; i++)
    #pragma unroll
    for (int j = 0; j < 4; j++) {
      float s = 0.f;
      #pragma unroll
      for (int k = 0; k < 4; k++) s += A[i*4+k] * B[k*4+j];
      C[i*4+j] = s;
    }
}

// Forward rot_block PTM (verified by the round-3 passing kernel):
// T2 = [D1*Rz(al)] * [PD*AD*D1*Rx(th)] * [D1*Rz(ph)], ang = (th, ph, al).
static __device__ __forceinline__ void rotfull(const float* ang, float lam1,
                                               float k1, float g1, float h1,
                                               float* T2) {
  float s1, c1, s2, c2, s3, c3;
  sincosf(ang[1], &s1, &c1);   // phi   (first rz)
  sincosf(ang[0], &s2, &c2);   // theta (rx)
  sincosf(ang[2], &s3, &c3);   // alpha (last rz)
  float Z1[16] = {1,0,0,0, 0,lam1*c1,-lam1*s1,0, 0,lam1*s1,lam1*c1,0, 0,0,0,lam1};
  float BR[16] = {1,0,0,0, 0,k1,0,0, 0,0,k1*c2,-k1*s2, g1,0,h1*s2,h1*c2};
  float Z2[16] = {1,0,0,0, 0,lam1*c3,-lam1*s3,0, 0,lam1*s3,lam1*c3,0, 0,0,0,lam1};
  float T1[16];
  mul4(BR, Z1, T1);
  mul4(Z2, T1, T2);
}

// w' = M^T w along the axis with stride S (S in {16,4,1}); fully unrolled.
template<int S>
static __device__ __forceinline__ void applyMT(float* w, const float* M) {
  #pragma unroll
  for (int u = 0; u < 4; u++)
    #pragma unroll
    for (int v = 0; v < 4; v++) {
      const int base = (S == 16) ? (u*4 + v) : (S == 4) ? (u*16 + v) : (u*16 + v*4);
      const float f0 = w[base], f1 = w[base+S], f2 = w[base+2*S], f3 = w[base+3*S];
      w[base]     = f0*M[0] + f1*M[4] + f2*M[8]  + f3*M[12];
      w[base+S]   = f0*M[1] + f1*M[5] + f2*M[9]  + f3*M[13];
      w[base+2*S] = f0*M[2] + f1*M[6] + f2*M[10] + f3*M[14];
      w[base+3*S] = f0*M[3] + f1*M[7] + f2*M[11] + f3*M[15];
    }
}

// Dual of the rzz per-qubit noise N2 (X,Y *= n; Z-row (g,0,0,h)), transposed:
// wI += g*wZ; wX *= n; wY *= n; wZ *= h.   Along stride S.
template<int S>
static __device__ __forceinline__ void applyN2T(float* w, float n2, float g2, float h2) {
  #pragma unroll
  for (int u = 0; u < 4; u++)
    #pragma unroll
    for (int v = 0; v < 4; v++) {
      const int base = (S == 16) ? (u*4 + v) : (S == 4) ? (u*16 + v) : (u*16 + v*4);
      w[base]    += g2 * w[base+3*S];
      w[base+S]  *= n2;
      w[base+2*S] *= n2;
      w[base+3*S] *= h2;
    }
}

// Transposed rzz rotation on axes (stride Sa = qubit q, Sb = qubit q+1),
// Sc = stride of the remaining digit. Forward planes (verified):
//   (XI,YZ),(XZ,YI),(IX,ZY),(ZX,IY) each rotated by [[c,-s],[s,c]];
// transpose = [[c,s],[-s,c]].
template<int Sa, int Sb, int Sc>
static __device__ __forceinline__ void applyRzzT(float* w, float c, float s) {
  #pragma unroll
  for (int r = 0; r < 4; r++) {
    const int B0 = r * Sc;
    #define F(m) w[B0 + ((m) >> 2) * Sa + ((m) & 3) * Sb]
    float t;
    t = c*F(4)  + s*F(11); F(11) = -s*F(4)  + c*F(11); F(4)  = t;  // XI / YZ
    t = c*F(7)  + s*F(8);  F(8)  = -s*F(7)  + c*F(8);  F(7)  = t;  // XZ / YI
    t = c*F(1)  + s*F(14); F(14) = -s*F(1)  + c*F(14); F(1)  = t;  // IX / ZY
    t = c*F(13) + s*F(2);  F(2)  = -s*F(13) + c*F(2);  F(13) = t;  // ZX / IY
    #undef F
  }
}

__global__ __launch_bounds__(64) void qnn_lc(
    const float* __restrict__ x, const float* __restrict__ fminp,
    const float* __restrict__ qw, const float* __restrict__ dk,
    const float* __restrict__ db, float* __restrict__ out, int B,
    float lam1, float k1, float g1, float h1,
    float n2, float g2, float h2) {
  const int b = blockIdx.x * 64 + threadIdx.x;

  // Backward-evolved observable w (identical in every thread; all registers).
  float w[64];
  #pragma unroll
  for (int i = 0; i < 64; i++) w[i] = 0.f;
  w[48] = 1.f;                       // Z (x) I (x) I

  float T[16];
  float s, c;

  // FINrot0^T  (fin[0] at qw[62])
  rotfull(qw + 62, lam1, k1, g1, h1, T); applyMT<16>(w, T);
  // L2 zz01^T  (e[0][1][0] = qw[55]); dual order: N2^T(q1), N2^T(q0), Rzz^T
  sincosf(qw[55], &s, &c);
  applyN2T<4>(w, n2, g2, h2); applyN2T<16>(w, n2, g2, h2); applyRzzT<16,4,1>(w, c, s);
  // L2 rot1^T (qw[27]), L2 rot0^T (qw[24])
  rotfull(qw + 27, lam1, k1, g1, h1, T); applyMT<4>(w, T);
  rotfull(qw + 24, lam1, k1, g1, h1, T); applyMT<16>(w, T);
  // L1 zz12^T (e[0][0][1] = qw[49])
  sincosf(qw[49], &s, &c);
  applyN2T<1>(w, n2, g2, h2); applyN2T<4>(w, n2, g2, h2); applyRzzT<4,1,16>(w, c, s);
  // L1 zz01^T (e[0][0][0] = qw[48])
  sincosf(qw[48], &s, &c);
  applyN2T<4>(w, n2, g2, h2); applyN2T<16>(w, n2, g2, h2); applyRzzT<16,4,1>(w, c, s);
  // L1 rot2^T (qw[6]), rot1^T (qw[3]), rot0^T (qw[0])
  rotfull(qw + 6, lam1, k1, g1, h1, T); applyMT<1>(w, T);
  rotfull(qw + 3, lam1, k1, g1, h1, T); applyMT<4>(w, T);
  rotfull(qw + 0, lam1, k1, g1, h1, T); applyMT<16>(w, T);

  // Per-batch contraction with the encoded product state.
  if (b < B) {
    const float fm = fminp[0];
    float r[3][4];
    #pragma unroll
    for (int q = 0; q < 3; q++) {
      float sq, cq;
      sincosf(x[b*8 + q] * fm, &sq, &cq);
      r[q][0] = 1.f; r[q][1] = 0.f; r[q][2] = -k1 * sq; r[q][3] = g1 + h1 * cq;
    }
    float acc = 0.f;
    #pragma unroll
    for (int i = 0; i < 4; i++) {
      const float ai = r[0][i];
      #pragma unroll
      for (int j = 0; j < 4; j++) {
        const float aj = ai * r[1][j];
        #pragma unroll
        for (int k = 0; k < 4; k++) acc += w[i*16 + j*4 + k] * aj * r[2][k];
      }
    }
    out[b] = acc * dk[0] + db[0];
  }
}

extern "C" void kernel_launch(void* const* d_in, const int* in_sizes, int n_in,
                              void* d_out, int out_size, void* d_ws, size_t ws_size,
                              hipStream_t stream) {
  (void)n_in; (void)d_ws; (void)ws_size; (void)out_size;
  const float* x    = (const float*)d_in[0];   // (B,8)
  const float* fmin = (const float*)d_in[1];   // (1,)
  const float* qw   = (const float*)d_in[2];   // (86,)
  const float* dk   = (const float*)d_in[3];   // (1,1)
  const float* db   = (const float*)d_in[4];   // (1,)
  float* out = (float*)d_out;                  // float32 (B,1)

  const int B = in_sizes[0] / 8;

  // IBM Kingston noise constants (double precision on host).
  const double EPC1 = 0.0002335, EPC2 = 0.002137;
  const double T1 = 0.00022438, T2 = 0.00012053;
  const double TRX = 3.5e-8, TZZ = 2.5e-7;
  const double lam1 = 1.0 - 4.0*EPC1/3.0;          // depol1 X,Y,Z scale
  const double lam2 = 1.0 - 4.0*EPC2/3.0;          // depol2
  const double gad1 = 1.0 - exp(-TRX/T1);          // AD gamma (rx)
  const double gpd1 = 1.0 - exp(-TRX/T2);          // PD gamma (rx)
  const double gad2 = 1.0 - exp(-TZZ/T1);          // AD gamma (rzz)
  const double gpd2 = 1.0 - exp(-TZZ/T2);          // PD gamma (rzz)
  const float k1f = (float)(sqrt((1.0-gpd1)*(1.0-gad1)) * lam1);
  const float g1f = (float)gad1;
  const float h1f = (float)((1.0-gad1) * lam1);
  const float n2f = (float)(sqrt((1.0-gpd2)*(1.0-gad2)) * lam2);
  const float g2f = (float)gad2;
  const float h2f = (float)((1.0-gad2) * lam2);

  const int blocks = (B + 63) / 64;
  qnn_lc<<<blocks, 64, 0, stream>>>(x, fmin, qw, dk, db, out, B,
                                    (float)lam1, k1f, g1f, h1f,
                                    n2f, g2f, h2f);
}

// Round 5
// 9.688 us; speedup vs baseline: 13.8889x; 1.3117x over previous
//
#include <hip/hip_runtime.h>
#include <cmath>

// ---------------------------------------------------------------------------
// Light-cone-reduced noisy QNN, wave-cooperative version.
//
// Backward (Heisenberg) propagation of Z_0 has support {q0,q1,q2} only.
// The 64-dim real Pauli-coefficient vector w[p0*16+p1*4+p2] is DISTRIBUTED:
// lane l holds w[l]. Axis transforms become 3 shuffles + 4 broadcast LDS
// coefficient reads + 4 FMA; rzz planes are all xor(3,3) pairs -> 1 shuffle.
// The 6 weight-dependent 4x4 PTMs are built concurrently by lanes 0-5.
// Stage sequence is a 1:1 transcription of the round-4 verified kernel:
//   FINrot0^T, [N2T(q1),N2T(q0),RzzT01](qw55), L2rot1^T, L2rot0^T,
//   [N2T(q2),N2T(q1),RzzT12](qw49), [N2T(q1),N2T(q0),RzzT01](qw48),
//   L1rot2^T, L1rot1^T, L1rot0^T.
// Then out_b = (sum_p w[p] * r0[p0]*r1[p1]*r2[p2]) * dk + db,
//   r_q = (1, 0, -k1*sin(x_q*fmin), g1 + h1*cos(x_q*fmin)).
// ---------------------------------------------------------------------------

static __device__ __forceinline__ void mul4(const float* A, const float* B, float* C) {
  #pragma unroll
  for (int i = 0; i < 4; i++)
    #pragma unroll
    for (int j = 0; j < 4; j++) {
      float s = 0.f;
      #pragma unroll
      for (int k = 0; k < 4; k++) s += A[i*4+k] * B[k*4+j];
      C[i*4+j] = s;
    }
}

__global__ __launch_bounds__(64) void qnn_lc2(
    const float* __restrict__ x, const float* __restrict__ fminp,
    const float* __restrict__ qw, const float* __restrict__ dk,
    const float* __restrict__ db, float* __restrict__ out, int B,
    float lam1, float k1, float g1, float h1,
    float n2, float g2, float h2) {
  __shared__ float M[6][16];   // forward PTMs; applied transposed via column reads
  __shared__ float ZC[3], ZS[3];
  __shared__ float WV[64];

  const int l = threadIdx.x;

  // ---- build the 6 rot-block PTMs (lanes 0-5) and 3 zz sincos (lanes 8-10) ----
  if (l < 6) {
    const int off = l==0 ? 62 : l==1 ? 27 : l==2 ? 24 : l==3 ? 6 : l==4 ? 3 : 0;
    const float* ang = qw + off;              // (theta, phi, alpha)
    const float s1 = __sinf(ang[1]), c1 = __cosf(ang[1]);  // phi   (first rz)
    const float s2 = __sinf(ang[0]), c2 = __cosf(ang[0]);  // theta (rx)
    const float s3 = __sinf(ang[2]), c3 = __cosf(ang[2]);  // alpha (last rz)
    float Z1[16] = {1,0,0,0, 0,lam1*c1,-lam1*s1,0, 0,lam1*s1,lam1*c1,0, 0,0,0,lam1};
    float BR[16] = {1,0,0,0, 0,k1,0,0, 0,0,k1*c2,-k1*s2, g1,0,h1*s2,h1*c2};
    float Z2[16] = {1,0,0,0, 0,lam1*c3,-lam1*s3,0, 0,lam1*s3,lam1*c3,0, 0,0,0,lam1};
    float T1[16], T2[16];
    mul4(BR, Z1, T1);
    mul4(Z2, T1, T2);                          // T2 = Z2 * BR * Z1 (forward PTM)
    #pragma unroll
    for (int i = 0; i < 16; i++) M[l][i] = T2[i];
  } else if (l >= 8 && l < 11) {
    const int j = l - 8;
    const float a = qw[j==0 ? 55 : j==1 ? 49 : 48];
    ZS[j] = __sinf(a); ZC[j] = __cosf(a);
  }
  __syncthreads();

  // ---- distributed observable: lane l holds w[l]; start at Z (x) I (x) I ----
  float w = (l == 48) ? 1.f : 0.f;

  // w' = M^T w along axis with lane-shift sh (p0:4, p1:2, p2:0).
  auto applyMT = [&](int m, int sh) {
    const int d = (l >> sh) & 3;
    const float v1 = __shfl_xor(w, 1 << sh);
    const float v2 = __shfl_xor(w, 2 << sh);
    const float v3 = __shfl_xor(w, 3 << sh);
    const float* Mm = M[m];
    const float a0 = Mm[d*4 + d];             // in = d     (own value)
    const float a1 = Mm[(d^1)*4 + d];
    const float a2 = Mm[(d^2)*4 + d];
    const float a3 = Mm[(d^3)*4 + d];
    w = w*a0 + v1*a1 + v2*a2 + v3*a3;
  };
  // Dual rzz noise (transposed): I += g*Z; X,Y *= n; Z *= h.
  auto applyN2T = [&](int sh) {
    const int d = (l >> sh) & 3;
    const float p3 = __shfl_xor(w, 3 << sh);  // old value at digit d^3
    float nw = (d == 3) ? h2 * w : n2 * w;
    nw = (d == 0) ? w + g2 * p3 : nw;
    w = nw;
  };
  // Transposed rzz rotation on axes (shA = qubit q, shB = qubit q+1):
  // pairs are xor(3,3) on (dA,dB); in-pair iff exactly one digit in {1,2};
  // A-side iff that digit == 1;  A' = c*A + s*B,  B' = -s*A + c*B.
  auto applyRzzT = [&](int zi, int shA, int shB) {
    const int dA = (l >> shA) & 3, dB = (l >> shB) & 3;
    const bool a12 = (dA == 1) | (dA == 2);
    const bool b12 = (dB == 1) | (dB == 2);
    const bool inp = a12 ^ b12;
    const bool isA = a12 ? (dA == 1) : (dB == 1);
    const float c = ZC[zi], s = ZS[zi];
    const float p = __shfl_xor(w, (3 << shA) | (3 << shB));
    const float rot = c * w + (isA ? s * p : -s * p);
    w = inp ? rot : w;
  };

  // ---- backward chain (exact round-4 verified order) ----
  applyMT(0, 4);                               // FINrot0^T        (qw+62)
  applyN2T(2); applyN2T(4); applyRzzT(0, 4, 2);// L2 zz01^T        (qw[55])
  applyMT(1, 2);                               // L2 rot1^T        (qw+27)
  applyMT(2, 4);                               // L2 rot0^T        (qw+24)
  applyN2T(0); applyN2T(2); applyRzzT(1, 2, 0);// L1 zz12^T        (qw[49])
  applyN2T(2); applyN2T(4); applyRzzT(2, 4, 2);// L1 zz01^T        (qw[48])
  applyMT(3, 0);                               // L1 rot2^T        (qw+6)
  applyMT(4, 2);                               // L1 rot1^T        (qw+3)
  applyMT(5, 4);                               // L1 rot0^T        (qw+0)

  WV[l] = w;
  __syncthreads();

  // ---- per-batch contraction with the encoded product state ----
  const int b = blockIdx.x * 64 + l;
  if (b < B) {
    const float fm = fminp[0];
    float r0[4], r1[4], r2[4];
    {
      const float a0 = x[b*8 + 0] * fm;
      const float a1 = x[b*8 + 1] * fm;
      const float a2 = x[b*8 + 2] * fm;
      r0[0] = 1.f; r0[1] = 0.f; r0[2] = -k1 * __sinf(a0); r0[3] = g1 + h1 * __cosf(a0);
      r1[0] = 1.f; r1[1] = 0.f; r1[2] = -k1 * __sinf(a1); r1[3] = g1 + h1 * __cosf(a1);
      r2[0] = 1.f; r2[1] = 0.f; r2[2] = -k1 * __sinf(a2); r2[3] = g1 + h1 * __cosf(a2);
    }
    float acc = 0.f;
    const int idx[3] = {0, 2, 3};              // r[1] = 0: skip
    #pragma unroll
    for (int ii = 0; ii < 3; ii++) {
      const int i = idx[ii];
      #pragma unroll
      for (int jj = 0; jj < 3; jj++) {
        const int j = idx[jj];
        const float rij = r0[i] * r1[j];
        #pragma unroll
        for (int kk = 0; kk < 3; kk++) {
          const int k = idx[kk];
          acc += WV[i*16 + j*4 + k] * rij * r2[k];
        }
      }
    }
    out[b] = acc * dk[0] + db[0];
  }
}

extern "C" void kernel_launch(void* const* d_in, const int* in_sizes, int n_in,
                              void* d_out, int out_size, void* d_ws, size_t ws_size,
                              hipStream_t stream) {
  (void)n_in; (void)d_ws; (void)ws_size; (void)out_size;
  const float* x    = (const float*)d_in[0];   // (B,8)
  const float* fmin = (const float*)d_in[1];   // (1,)
  const float* qw   = (const float*)d_in[2];   // (86,)
  const float* dk   = (const float*)d_in[3];   // (1,1)
  const float* db   = (const float*)d_in[4];   // (1,)
  float* out = (float*)d_out;                  // float32 (B,1)

  const int B = in_sizes[0] / 8;

  // IBM Kingston noise constants (double precision on host).
  const double EPC1 = 0.0002335, EPC2 = 0.002137;
  const double T1 = 0.00022438, T2 = 0.00012053;
  const double TRX = 3.5e-8, TZZ = 2.5e-7;
  const double lam1 = 1.0 - 4.0*EPC1/3.0;          // depol1 X,Y,Z scale
  const double lam2 = 1.0 - 4.0*EPC2/3.0;          // depol2
  const double gad1 = 1.0 - exp(-TRX/T1);          // AD gamma (rx)
  const double gpd1 = 1.0 - exp(-TRX/T2);          // PD gamma (rx)
  const double gad2 = 1.0 - exp(-TZZ/T1);          // AD gamma (rzz)
  const double gpd2 = 1.0 - exp(-TZZ/T2);          // PD gamma (rzz)
  const float k1f = (float)(sqrt((1.0-gpd1)*(1.0-gad1)) * lam1);
  const float g1f = (float)gad1;
  const float h1f = (float)((1.0-gad1) * lam1);
  const float n2f = (float)(sqrt((1.0-gpd2)*(1.0-gad2)) * lam2);
  const float g2f = (float)gad2;
  const float h2f = (float)((1.0-gad2) * lam2);

  const int blocks = (B + 63) / 64;
  qnn_lc2<<<blocks, 64, 0, stream>>>(x, fmin, qw, dk, db, out, B,
                                     (float)lam1, k1f, g1f, h1f,
                                     n2f, g2f, h2f);
}